// Round 5
// baseline (316.111 us; speedup 1.0000x reference)
//
#include <hip/hip_runtime.h>
#include <hip/hip_bf16.h>
#include <stdint.h>
#include <math.h>

// ---- problem constants ----
#define NB 16
#define NC 512
#define NH 64
#define NW 64
#define HW 4096              // NH*NW
#define TILE_H 8             // 8x16 pixel tile per block (halved vs r4: acc 72/wave, LDS 43KB -> 2 blocks/CU)
#define TILE_W 16
#define HALO_H 16            // TILE_H + 8
#define HALO_W 24            // TILE_W + 8
#define NHALO (HALO_H * HALO_W)   // 384
#define A_ROWS (TILE_H * TILE_W)  // 128
#define KC 32                // channels per K chunk (one MFMA k-step)
#define NCH (NC / KC)        // 16 chunks
#define ROWB 80              // LDS bytes per pixel row: 32 bf16 = 64B + 16B pad (8-slot bank spread)
#define A_BASE 0
#define B_BASE (A_ROWS * ROWB)            // 10240
#define S_BASE (B_BASE + NHALO * ROWB)    // 40960
#define LDS_BYTES (S_BASE + 512 * 4)      // 43008  (x2 = 86KB < 160KB -> 2 blocks/CU)

using f32x4  = __attribute__((ext_vector_type(4))) float;
using bf16x8 = __attribute__((ext_vector_type(8))) short;
using i32x4  = __attribute__((ext_vector_type(4))) int;

// fp32 -> bf16 bits, round-to-nearest-even (inputs are finite normals)
__device__ __forceinline__ unsigned bf16r(float x) {
  unsigned u = __float_as_uint(x);
  u += 0x7fffu + ((u >> 16) & 1u);
  return u >> 16;
}

__global__ __launch_bounds__(512, 4)   // 4 waves/EU = 16 waves/CU -> <=128 regs/wave
void corr_mfma(const float* __restrict__ f1, const float* __restrict__ f2,
               float* __restrict__ out)
{
  alignas(16) __shared__ unsigned char smem[LDS_BYTES];
  float* snorm = reinterpret_cast<float*>(smem + S_BASE);

  const int tid = threadIdx.x;

  // ---- XCD-aware bijective remap: 512 blocks = 8 XCDs x 64; each XCD owns
  // 2 complete batches -> halo overlaps / half-line partners are same-XCD L2 hits.
  const int blk  = blockIdx.x;              // 0..511
  const int xcd  = blk & 7;
  const int slot = blk >> 3;                // 0..63
  const int b    = xcd * 2 + (slot >> 5);   // batch
  const int t5   = slot & 31;               // tile id within 8x4 grid
  const int y0   = (t5 >> 2) * TILE_H;
  const int x0   = (t5 & 3) * TILE_W;

  const int lane = tid & 63;
  const int lr   = lane & 15;          // frag row/col select
  const int lk   = lane >> 4;          // k-group (0..3)
  const int wv   = tid >> 6;           // wave id (0..7) == tile row ty

  // ---- staging: exactly one slot per thread ----
  // slots [0,128)   : f1 tile pixels (ty = s>>4, tx = s&15)
  // slots [128,512) : f2 halo, h = s-128, hy = h/24, hx = h%24
  const float* gptr;
  uint32_t     lbase;
  bool         ok;
  {
    const int s = tid;
    if (s < A_ROWS) {
      const int ty = s >> 4, tx = s & 15;
      gptr  = f1 + (size_t)b * NC * HW + (size_t)(y0 + ty) * NW + (x0 + tx);
      lbase = A_BASE + (uint32_t)s * ROWB;
      ok    = true;
    } else {
      const int h  = s - A_ROWS;
      const int hy = h / HALO_W, hx = h % HALO_W;   // compile-time divisor -> magic mul
      const int yy = y0 - 4 + hy, xx = x0 - 4 + hx;
      const bool v = ((unsigned)yy < NH) && ((unsigned)xx < NW);
      const size_t off = v ? ((size_t)b * NC * HW + (size_t)yy * NW + xx) : (size_t)0;
      gptr  = f2 + off;
      lbase = B_BASE + (uint32_t)h * ROWB;
      ok    = v;
    }
  }

  // ---- accumulators: wave owns row ty=wv x 9 dh x 2 N-tiles (72 f32) ----
  f32x4 acc[9][2];
  #pragma unroll
  for (int j = 0; j < 9; ++j)
    #pragma unroll
    for (int k = 0; k < 2; ++k) {
      f32x4 z = {0.f, 0.f, 0.f, 0.f};
      acc[j][k] = z;
    }

  float ss = 0.f;

  for (int kc = 0; kc < NCH; ++kc) {
    // ---------- stage chunk: global fp32 -> bf16 LDS [pixel][c], + sumsq ----------
    {
      const float* gp = gptr + (size_t)kc * KC * HW;
      float v[KC];
      if (ok) {
        #pragma unroll
        for (int k = 0; k < KC; ++k) v[k] = gp[(size_t)k * HW];
      } else {
        #pragma unroll
        for (int k = 0; k < KC; ++k) v[k] = 0.f;
      }
      float ps = 0.f;
      #pragma unroll
      for (int k = 0; k < KC; ++k) ps = fmaf(v[k], v[k], ps);
      ss += ps;

      unsigned char* lp = smem + lbase;
      #pragma unroll
      for (int j = 0; j < 4; ++j) {
        i32x4 w;
        #pragma unroll
        for (int q = 0; q < 4; ++q) {
          const unsigned lo = bf16r(v[j * 8 + 2 * q]);
          const unsigned hi = bf16r(v[j * 8 + 2 * q + 1]);
          w[q] = (int)((hi << 16) | lo);
        }
        *reinterpret_cast<i32x4*>(lp + j * 16) = w;
      }
    }
    __syncthreads();

    // ---------- banded MFMA over this k-step ----------
    // A-frag: f1 pixel (row wv, col lr); B-frag: halo pixel (hy=wv+dh, hx=8*hx0+lr)
    const bf16x8 afr = *reinterpret_cast<const bf16x8*>(
        smem + A_BASE + (uint32_t)(wv * 16 + lr) * ROWB + lk * 16);
    #pragma unroll
    for (int dh = 0; dh < 9; ++dh) {
      const int hy = wv + dh;
      #pragma unroll
      for (int hx0 = 0; hx0 < 2; ++hx0) {
        const bf16x8 bfr = *reinterpret_cast<const bf16x8*>(
            smem + B_BASE + (uint32_t)(hy * HALO_W + hx0 * 8 + lr) * ROWB + lk * 16);
        acc[dh][hx0] =
            __builtin_amdgcn_mfma_f32_16x16x32_bf16(afr, bfr, acc[dh][hx0], 0, 0, 0);
      }
    }
    __syncthreads();
  }

  // ---------- norms: snorm[i] = 1/sqrt(sumsq + 1e-6) ----------
  snorm[tid] = ss;
  __syncthreads();
  {
    const float t = snorm[tid];
    snorm[tid] = 1.0f / sqrtf(t + 1e-6f);
  }
  __syncthreads();

  // ---------- epilogue: scale, relu, banded scatter ----------
  // Two N-tiles at hx offsets {0,8} overlap for hx in [8,15]: both compute the
  // identical value and write the same address twice (deterministic, benign).
  float* op = out + (size_t)b * 81 * HW;
  #pragma unroll
  for (int dh = 0; dh < 9; ++dh) {
    const int hy = wv + dh;
    #pragma unroll
    for (int hx0 = 0; hx0 < 2; ++hx0) {
      const f32x4 a4 = acc[dh][hx0];
      const float i2 = snorm[A_ROWS + hy * HALO_W + hx0 * 8 + lr];  // lane's halo px
      #pragma unroll
      for (int r = 0; r < 4; ++r) {
        const int m  = lk * 4 + r;             // tile x (C/D row)
        const int dw = hx0 * 8 + lr - m;       // displacement = hx - m
        if (dw >= 0 && dw < 9) {
          const float i1 = snorm[wv * 16 + m];
          float val = a4[r] * i1 * i2;
          val = fmaxf(val, 0.f);
          op[(size_t)(dh * 9 + dw) * HW + (size_t)(y0 + wv) * NW + (x0 + m)] = val;
        }
      }
    }
  }
}

extern "C" void kernel_launch(void* const* d_in, const int* in_sizes, int n_in,
                              void* d_out, int out_size, void* d_ws, size_t ws_size,
                              hipStream_t stream) {
  (void)in_sizes; (void)n_in; (void)out_size; (void)d_ws; (void)ws_size;
  const float* f1 = (const float*)d_in[0];
  const float* f2 = (const float*)d_in[1];
  float* out = (float*)d_out;
  corr_mfma<<<dim3(512), dim3(512), 0, stream>>>(f1, f2, out);
}

// Round 6
// 315.097 us; speedup vs baseline: 1.0032x; 1.0032x over previous
//
#include <hip/hip_runtime.h>
#include <hip/hip_bf16.h>
#include <stdint.h>
#include <math.h>

// ---- problem constants ----
#define NB 16
#define NC 512
#define NH 64
#define NW 64
#define HW 4096              // NH*NW
#define TILE_H 8             // 8x16 pixel tile per block
#define TILE_W 16
#define HALO_H 16            // TILE_H + 8
#define HALO_W 24            // TILE_W + 8
#define NHALO (HALO_H * HALO_W)   // 384
#define A_ROWS (TILE_H * TILE_W)  // 128
#define NROWS (A_ROWS + NHALO)    // 512 rows per buffer (1 slot/thread)
#define KC 32                // channels per K chunk (one MFMA k-step)
#define NCH (NC / KC)        // 16 chunks
#define ROWB 80              // LDS bytes per pixel row: 32 bf16 = 64B + 16B pad
// double-buffered LDS + norms
#define BUF0 0u
#define BUF1 (NROWS * ROWB)               // 40960
#define SN_BASE (2u * NROWS * ROWB)       // 81920
#define LDS_BYTES (SN_BASE + NROWS * 4)   // 83968 -> 1 block/CU

using f32x4  = __attribute__((ext_vector_type(4))) float;
using bf16x8 = __attribute__((ext_vector_type(8))) short;
using i32x4  = __attribute__((ext_vector_type(4))) int;

// fp32 -> bf16 bits, round-to-nearest-even (inputs are finite normals)
__device__ __forceinline__ unsigned bf16r(float x) {
  unsigned u = __float_as_uint(x);
  u += 0x7fffu + ((u >> 16) & 1u);
  return u >> 16;
}

__global__ __launch_bounds__(512, 2)   // 2 waves/EU min: <=256 regs, 1 block/CU
void corr_mfma(const float* __restrict__ f1, const float* __restrict__ f2,
               float* __restrict__ out)
{
  alignas(16) __shared__ unsigned char smem[LDS_BYTES];
  float* snorm = reinterpret_cast<float*>(smem + SN_BASE);

  const int tid = threadIdx.x;

  // ---- XCD-aware bijective remap: 512 blocks = 8 XCDs x 64; each XCD owns
  // 2 complete batches -> halo overlaps / half-line partners are same-XCD L2 hits.
  const int blk  = blockIdx.x;              // 0..511
  const int xcd  = blk & 7;
  const int slot = blk >> 3;                // 0..63
  const int b    = xcd * 2 + (slot >> 5);   // batch
  const int t5   = slot & 31;               // tile id within 8x4 grid
  const int y0   = (t5 >> 2) * TILE_H;
  const int x0   = (t5 & 3) * TILE_W;

  const int lane = tid & 63;
  const int lr   = lane & 15;          // frag row/col select
  const int lk   = lane >> 4;          // k-group (0..3)
  const int wv   = tid >> 6;           // wave id (0..7) == tile row ty

  // ---- staging: exactly one slot per thread ----
  // slots [0,128)   : f1 tile pixels (ty = s>>4, tx = s&15)
  // slots [128,512) : f2 halo, h = s-128, hy = h/24, hx = h%24
  const float* gptr;
  uint32_t     rowoff;      // byte offset of this thread's row within a buffer
  bool         ok;
  {
    const int s = tid;
    if (s < A_ROWS) {
      const int ty = s >> 4, tx = s & 15;
      gptr   = f1 + (size_t)b * NC * HW + (size_t)(y0 + ty) * NW + (x0 + tx);
      rowoff = (uint32_t)s * ROWB;
      ok     = true;
    } else {
      const int h  = s - A_ROWS;
      const int hy = h / HALO_W, hx = h % HALO_W;
      const int yy = y0 - 4 + hy, xx = x0 - 4 + hx;
      const bool v = ((unsigned)yy < NH) && ((unsigned)xx < NW);
      const size_t off = v ? ((size_t)b * NC * HW + (size_t)yy * NW + xx) : (size_t)0;
      gptr   = f2 + off;
      rowoff = (uint32_t)s * ROWB;
      ok     = v;
    }
  }

  // ---- accumulators: wave owns row ty=wv x 9 dh x 2 N-tiles (72 f32) ----
  f32x4 acc[9][2];
  #pragma unroll
  for (int j = 0; j < 9; ++j)
    #pragma unroll
    for (int k = 0; k < 2; ++k) {
      f32x4 z = {0.f, 0.f, 0.f, 0.f};
      acc[j][k] = z;
    }

  float ss = 0.f;
  float v[KC];

  // ---- helpers (inlined; buffer bases are compile-time constants at call site) ----
  auto load_chunk = [&](int kc) {
    const float* gp = gptr + (size_t)kc * KC * HW;
    if (ok) {
      #pragma unroll
      for (int k = 0; k < KC; ++k) v[k] = gp[(size_t)k * HW];
    } else {
      #pragma unroll
      for (int k = 0; k < KC; ++k) v[k] = 0.f;
    }
  };

  auto store_chunk = [&](uint32_t base) {
    float ps = 0.f;
    #pragma unroll
    for (int k = 0; k < KC; ++k) ps = fmaf(v[k], v[k], ps);
    ss += ps;
    unsigned char* lp = smem + base + rowoff;
    #pragma unroll
    for (int j = 0; j < 4; ++j) {
      i32x4 w;
      #pragma unroll
      for (int q = 0; q < 4; ++q) {
        const unsigned lo = bf16r(v[j * 8 + 2 * q]);
        const unsigned hi = bf16r(v[j * 8 + 2 * q + 1]);
        w[q] = (int)((hi << 16) | lo);
      }
      *reinterpret_cast<i32x4*>(lp + j * 16) = w;
    }
  };

  auto compute_chunk = [&](uint32_t base) {
    // A-frag: f1 pixel (row wv, col lr); B-frag: halo pixel (hy=wv+dh, hx=8*hx0+lr)
    const bf16x8 afr = *reinterpret_cast<const bf16x8*>(
        smem + base + (uint32_t)(wv * 16 + lr) * ROWB + lk * 16);
    #pragma unroll
    for (int dh = 0; dh < 9; ++dh) {
      const int hy = wv + dh;
      #pragma unroll
      for (int hx0 = 0; hx0 < 2; ++hx0) {
        const bf16x8 bfr = *reinterpret_cast<const bf16x8*>(
            smem + base + (uint32_t)(A_ROWS + hy * HALO_W + hx0 * 8 + lr) * ROWB + lk * 16);
        acc[dh][hx0] =
            __builtin_amdgcn_mfma_f32_16x16x32_bf16(afr, bfr, acc[dh][hx0], 0, 0, 0);
      }
    }
  };

  // ---- software-pipelined chunk loop (double-buffered LDS) ----
  // iter(kc, CUR, NXT): issue loads for kc+1 EARLY; compute kc from CUR
  // (covers the load latency; no barrier in between); cvt+write kc+1 -> NXT;
  // one barrier per chunk. NXT was fully consumed before the PREVIOUS barrier.
  load_chunk(0);
  store_chunk(BUF0);
  __syncthreads();

  #define PIPE_ITER(KCC, CUR, NXT)  \
    load_chunk((KCC) + 1);          \
    compute_chunk(CUR);             \
    store_chunk(NXT);               \
    __syncthreads();

  for (int k2 = 0; k2 < 7; ++k2) {
    const int kc = 2 * k2;
    PIPE_ITER(kc,     BUF0, BUF1)
    PIPE_ITER(kc + 1, BUF1, BUF0)
  }
  PIPE_ITER(14, BUF0, BUF1)
  compute_chunk(BUF1);               // chunk 15, no prefetch
  #undef PIPE_ITER

  // ---------- norms: snorm[i] = 1/sqrt(sumsq + 1e-6) ----------
  snorm[tid] = ss;
  __syncthreads();
  {
    const float t = snorm[tid];
    snorm[tid] = 1.0f / sqrtf(t + 1e-6f);
  }
  __syncthreads();

  // ---------- epilogue: scale, relu, banded scatter ----------
  // Two N-tiles at hx offsets {0,8} overlap for hx in [8,15]: both compute the
  // identical value and write the same address twice (deterministic, benign).
  float* op = out + (size_t)b * 81 * HW;
  #pragma unroll
  for (int dh = 0; dh < 9; ++dh) {
    const int hy = wv + dh;
    #pragma unroll
    for (int hx0 = 0; hx0 < 2; ++hx0) {
      const f32x4 a4 = acc[dh][hx0];
      const float i2 = snorm[A_ROWS + hy * HALO_W + hx0 * 8 + lr];  // lane's halo px
      #pragma unroll
      for (int r = 0; r < 4; ++r) {
        const int m  = lk * 4 + r;             // tile x (C/D row)
        const int dw = hx0 * 8 + lr - m;       // displacement = hx - m
        if (dw >= 0 && dw < 9) {
          const float i1 = snorm[wv * 16 + m];
          float val = a4[r] * i1 * i2;
          val = fmaxf(val, 0.f);
          op[(size_t)(dh * 9 + dw) * HW + (size_t)(y0 + wv) * NW + (x0 + m)] = val;
        }
      }
    }
  }
}

extern "C" void kernel_launch(void* const* d_in, const int* in_sizes, int n_in,
                              void* d_out, int out_size, void* d_ws, size_t ws_size,
                              hipStream_t stream) {
  (void)in_sizes; (void)n_in; (void)out_size; (void)d_ws; (void)ws_size;
  const float* f1 = (const float*)d_in[0];
  const float* f2 = (const float*)d_in[1];
  float* out = (float*)d_out;
  corr_mfma<<<dim3(512), dim3(512), 0, stream>>>(f1, f2, out);
}